// Round 1
// baseline (3438.345 us; speedup 1.0000x reference)
//
#include <hip/hip_runtime.h>
#include <hip/hip_bf16.h>

// Problem constants (B,C,T,H,W = 2,128,4,32,32; L=6; N=T*H*W=4096)
#define BCNT 2
#define CCH  128
#define NTOK 4096
#define NLAY 6
#define INV_SQRT 0.015625f   // 1/sqrt(4096)

// ---------------------------------------------------------------------------
// Kernel 1: q/k/v = W @ x + bias  (per layer; which = 0:q 1:k 2:v)
// out[b][o][n] = sum_c W[o][c] * x[b][c][n] + bias[o]
// grid (N/64, 3, B), block 256. LDS: x-tile [128][68], W [128][129].
// ---------------------------------------------------------------------------
__global__ __launch_bounds__(256) void qkv_kernel(
    const float* __restrict__ x,
    const float* __restrict__ W1, const float* __restrict__ b1,
    const float* __restrict__ W2, const float* __restrict__ b2,
    const float* __restrict__ Wg, const float* __restrict__ bg,
    float* __restrict__ q, float* __restrict__ k, float* __restrict__ v,
    int layer)
{
  const int ntile = blockIdx.x * 64;
  const int which = blockIdx.y;
  const int b     = blockIdx.z;
  const float* W; const float* bias; float* out;
  if (which == 0)      { W = W1; bias = b1; out = q; }
  else if (which == 1) { W = W2; bias = b2; out = k; }
  else                 { W = Wg; bias = bg; out = v; }
  W += (size_t)layer * CCH * CCH; bias += (size_t)layer * CCH;

  __shared__ float xs[CCH][68];
  __shared__ float Wl[CCH][129];
  const float* xb = x + (size_t)b * CCH * NTOK;
  const int t = threadIdx.x;
  for (int i = t; i < CCH * 64; i += 256) {
    int cc = i >> 6, nn = i & 63;
    xs[cc][nn] = xb[(size_t)cc * NTOK + ntile + nn];
  }
  for (int i = t; i < CCH * CCH; i += 256) {
    int oo = i >> 7, cc = i & 127;
    Wl[oo][cc] = W[i];
  }
  __syncthreads();

  const int tn = (t & 15) * 4;   // 4 tokens
  const int to = (t >> 4) * 8;   // 8 output channels
  float accr[8][4];
  #pragma unroll
  for (int i = 0; i < 8; i++)
    #pragma unroll
    for (int j = 0; j < 4; j++) accr[i][j] = 0.f;

  for (int cc = 0; cc < CCH; ++cc) {
    float xv[4];
    #pragma unroll
    for (int j = 0; j < 4; j++) xv[j] = xs[cc][tn + j];
    #pragma unroll
    for (int i = 0; i < 8; i++) {
      float wv = Wl[to + i][cc];
      #pragma unroll
      for (int j = 0; j < 4; j++) accr[i][j] += wv * xv[j];
    }
  }
  float* ob = out + (size_t)b * CCH * NTOK;
  #pragma unroll
  for (int i = 0; i < 8; i++) {
    float bi = bias[to + i];
    float4 r = make_float4(accr[i][0] + bi, accr[i][1] + bi,
                           accr[i][2] + bi, accr[i][3] + bi);
    *reinterpret_cast<float4*>(&ob[(size_t)(to + i) * NTOK + ntile + tn]) = r;
  }
}

// ---------------------------------------------------------------------------
// Kernel 2: column sums D[b][m] = sum_n exp( (1/64) * sum_c q[c][n]*k[c][m] )
// grid (N/64 [n-tile], N/64 [m-tile], B), block 256, 4x4 micro-tiles.
// ---------------------------------------------------------------------------
__global__ __launch_bounds__(256) void dcol_kernel(
    const float* __restrict__ q, const float* __restrict__ k,
    float* __restrict__ D)
{
  const int ntile = blockIdx.x * 64, mtile = blockIdx.y * 64, b = blockIdx.z;
  __shared__ float qs[CCH][68];
  __shared__ float ks[CCH][68];
  __shared__ float red[16][64];
  const float* qb = q + (size_t)b * CCH * NTOK;
  const float* kb = k + (size_t)b * CCH * NTOK;
  const int t = threadIdx.x;
  for (int i = t; i < CCH * 64; i += 256) {
    int cc = i >> 6, nn = i & 63;
    qs[cc][nn] = qb[(size_t)cc * NTOK + ntile + nn];
    ks[cc][nn] = kb[(size_t)cc * NTOK + mtile + nn];
  }
  __syncthreads();

  const int tm = (t & 15) * 4, tn = (t >> 4) * 4;
  float s[4][4];
  #pragma unroll
  for (int i = 0; i < 4; i++)
    #pragma unroll
    for (int j = 0; j < 4; j++) s[i][j] = 0.f;

  for (int cc = 0; cc < CCH; ++cc) {
    float qv[4], kv[4];
    #pragma unroll
    for (int j = 0; j < 4; j++) { qv[j] = qs[cc][tn + j]; kv[j] = ks[cc][tm + j]; }
    #pragma unroll
    for (int i = 0; i < 4; i++)
      #pragma unroll
      for (int j = 0; j < 4; j++) s[i][j] += qv[i] * kv[j];
  }
  float psum[4];
  #pragma unroll
  for (int j = 0; j < 4; j++) {
    psum[j] = 0.f;
    #pragma unroll
    for (int i = 0; i < 4; i++) psum[j] += __expf(s[i][j] * INV_SQRT);
  }
  #pragma unroll
  for (int j = 0; j < 4; j++) red[t >> 4][tm + j] = psum[j];
  __syncthreads();
  if (t < 64) {
    float sum = 0.f;
    #pragma unroll
    for (int r = 0; r < 16; r++) sum += red[r][t];
    atomicAdd(&D[(size_t)b * NTOK + mtile + t], sum);
  }
}

// ---------------------------------------------------------------------------
// Kernel 3: v[b][c][m] *= 1 / (D[b][m] * L)    (folds the mean over layers)
// ---------------------------------------------------------------------------
__global__ __launch_bounds__(256) void scalev_kernel(
    float* __restrict__ v, const float* __restrict__ D)
{
  const int idx = blockIdx.x * 256 + threadIdx.x;   // over B*C*N = 2^20
  const int m = idx & (NTOK - 1);
  const int b = idx >> 19;                          // C*N = 2^19
  v[idx] *= 1.0f / (D[(size_t)b * NTOK + m] * (float)NLAY);
}

// ---------------------------------------------------------------------------
// Kernel 4: fused E = exp(S) recompute + PV:
//   acc[b][n][c] += sum_m exp(S[n][m]) * v'[c][m]
// grid (N/64 [n-tile], 4 [m-chunks of 1024], B), block 256.
// LDS: qs 34.0K + ks 18.0K + vs 17.0K + es 9.0K = ~78K -> 2 blocks/CU.
// ---------------------------------------------------------------------------
__global__ __launch_bounds__(256) void attn_pv_kernel(
    const float* __restrict__ q, const float* __restrict__ k,
    const float* __restrict__ v, float* __restrict__ acc)
{
  const int ntile = blockIdx.x * 64;
  const int mbase = blockIdx.y * 1024;
  const int b     = blockIdx.z;
  __shared__ float qs[CCH][68];
  __shared__ float ks[CCH][36];
  __shared__ float vs[32][136];
  __shared__ float es[64][36];
  const float* qb = q + (size_t)b * CCH * NTOK;
  const float* kb = k + (size_t)b * CCH * NTOK;
  const float* vb = v + (size_t)b * CCH * NTOK;
  const int t = threadIdx.x;

  for (int i = t; i < CCH * 64; i += 256) {
    int cc = i >> 6, nn = i & 63;
    qs[cc][nn] = qb[(size_t)cc * NTOK + ntile + nn];
  }
  const int tn = (t >> 4) * 4;   // 4 rows n
  const int tc = (t & 15) * 8;   // 8 channels c
  const int tm = (t & 15) * 2;   // 2 cols m (S phase)
  float oacc[4][8];
  #pragma unroll
  for (int i = 0; i < 4; i++)
    #pragma unroll
    for (int j = 0; j < 8; j++) oacc[i][j] = 0.f;

  for (int mt = 0; mt < 32; ++mt) {
    const int mtile = mbase + mt * 32;
    __syncthreads();  // prev-iter readers done before restaging
    for (int i = t; i < CCH * 32; i += 256) {
      int cc = i >> 5, mm = i & 31;
      ks[cc][mm] = kb[(size_t)cc * NTOK + mtile + mm];
    }
    for (int i = t; i < 32 * CCH; i += 256) {
      int mm = i & 31, cc = i >> 5;   // lanes walk mm fastest -> coalesced
      vs[mm][cc] = vb[(size_t)cc * NTOK + mtile + mm];
    }
    __syncthreads();

    // S phase: 4n x 2m per thread
    float s[4][2];
    #pragma unroll
    for (int i = 0; i < 4; i++) { s[i][0] = 0.f; s[i][1] = 0.f; }
    for (int cc = 0; cc < CCH; ++cc) {
      float qv[4];
      #pragma unroll
      for (int i = 0; i < 4; i++) qv[i] = qs[cc][tn + i];
      float kv[2];
      kv[0] = ks[cc][tm]; kv[1] = ks[cc][tm + 1];
      #pragma unroll
      for (int i = 0; i < 4; i++) { s[i][0] += qv[i] * kv[0]; s[i][1] += qv[i] * kv[1]; }
    }
    #pragma unroll
    for (int i = 0; i < 4; i++) {
      es[tn + i][tm]     = __expf(s[i][0] * INV_SQRT);
      es[tn + i][tm + 1] = __expf(s[i][1] * INV_SQRT);
    }
    __syncthreads();

    // PV phase: oacc[4n][8c] += sum_mm es[n][mm] * vs[mm][c]
    for (int mm = 0; mm < 32; ++mm) {
      float ev[4];
      #pragma unroll
      for (int i = 0; i < 4; i++) ev[i] = es[tn + i][mm];
      float vv[8];
      #pragma unroll
      for (int j = 0; j < 8; j++) vv[j] = vs[mm][tc + j];
      #pragma unroll
      for (int i = 0; i < 4; i++)
        #pragma unroll
        for (int j = 0; j < 8; j++) oacc[i][j] += ev[i] * vv[j];
    }
  }
  float* ab = acc + (size_t)b * NTOK * CCH;
  #pragma unroll
  for (int i = 0; i < 4; i++)
    #pragma unroll
    for (int j = 0; j < 8; j++)
      atomicAdd(&ab[(size_t)(ntile + tn + i) * CCH + tc + j], oacc[i][j]);
}

// ---------------------------------------------------------------------------
// Kernel 5: out[b][c][n] = acc[b][n][c] + x[b][c][n]
// ---------------------------------------------------------------------------
__global__ __launch_bounds__(256) void finalize_kernel(
    const float* __restrict__ acc, const float* __restrict__ x,
    float* __restrict__ out)
{
  const int idx = blockIdx.x * 256 + threadIdx.x;   // over B*C*N
  const int n = idx & (NTOK - 1);
  const int c = (idx >> 12) & (CCH - 1);
  const int b = idx >> 19;
  out[idx] = acc[((size_t)b * NTOK + n) * CCH + c] + x[idx];
}

// ---------------------------------------------------------------------------
extern "C" void kernel_launch(void* const* d_in, const int* in_sizes, int n_in,
                              void* d_out, int out_size, void* d_ws, size_t ws_size,
                              hipStream_t stream)
{
  const float* x  = (const float*)d_in[0];
  const float* W1 = (const float*)d_in[1];
  const float* b1 = (const float*)d_in[2];
  const float* W2 = (const float*)d_in[3];
  const float* b2 = (const float*)d_in[4];
  const float* Wg = (const float*)d_in[5];
  const float* bg = (const float*)d_in[6];
  float* out = (float*)d_out;

  // Workspace layout (floats). Total = 4*PLANE + B*N = ~16.8 MB.
  float* ws = (float*)d_ws;
  const size_t PLANE = (size_t)BCNT * CCH * NTOK;   // 1,048,576
  float* q    = ws;
  float* k    = q + PLANE;
  float* v    = k + PLANE;
  float* Dcol = v + PLANE;
  float* acc  = Dcol + (size_t)BCNT * NTOK;

  hipMemsetAsync(acc, 0, PLANE * sizeof(float), stream);
  for (int l = 0; l < NLAY; ++l) {
    qkv_kernel<<<dim3(NTOK / 64, 3, BCNT), 256, 0, stream>>>(
        x, W1, b1, W2, b2, Wg, bg, q, k, v, l);
    hipMemsetAsync(Dcol, 0, (size_t)BCNT * NTOK * sizeof(float), stream);
    dcol_kernel<<<dim3(NTOK / 64, NTOK / 64, BCNT), 256, 0, stream>>>(q, k, Dcol);
    scalev_kernel<<<dim3(PLANE / 256), 256, 0, stream>>>(v, Dcol);
    attn_pv_kernel<<<dim3(NTOK / 64, 4, BCNT), 256, 0, stream>>>(q, k, v, acc);
  }
  finalize_kernel<<<dim3(PLANE / 256), 256, 0, stream>>>(acc, x, out);
}

// Round 2
// 433.326 us; speedup vs baseline: 7.9348x; 7.9348x over previous
//
#include <hip/hip_runtime.h>
#include <hip/hip_bf16.h>

// Problem constants (B,C,T,H,W = 2,128,4,32,32; L=6; N=T*H*W=4096)
#define BCNT 2
#define CCH  128
#define NTOK 4096
#define NLAY 6
#define INV_SQRT 0.015625f   // 1/sqrt(4096)
#define LDP 136              // padded LDS cols for 128-wide bf16 tiles

using f32x4  = __attribute__((ext_vector_type(4))) float;
using bf16x8 = __attribute__((ext_vector_type(8))) short;

static __device__ __forceinline__ ushort f2bf(float f) {
  unsigned u = __float_as_uint(f);
  u += 0x7FFF + ((u >> 16) & 1);   // RNE
  return (ushort)(u >> 16);
}

// Stage a 128x128 bf16 tile (global row stride = gstride ushorts) into lds[128][LDP].
static __device__ __forceinline__ void stage_bf16(ushort (*lds)[LDP],
                                                  const ushort* __restrict__ g,
                                                  int gstride, int t) {
  #pragma unroll
  for (int p = 0; p < 8; ++p) {
    int idx = p * 256 + t;
    int row = idx >> 4, ch = (idx & 15) * 8;
    *(uint4*)&lds[row][ch] = *(const uint4*)(g + (size_t)row * gstride + ch);
  }
}

// Stage a 128x128 f32 tile (row stride 128) into lds bf16 [128][LDP].
static __device__ __forceinline__ void stage_f32(ushort (*lds)[LDP],
                                                 const float* __restrict__ g, int t) {
  #pragma unroll
  for (int p = 0; p < 16; ++p) {
    int idx = p * 256 + t;
    int row = idx >> 5, c4 = (idx & 31) * 4;
    float4 w = *(const float4*)(g + row * 128 + c4);
    lds[row][c4 + 0] = f2bf(w.x); lds[row][c4 + 1] = f2bf(w.y);
    lds[row][c4 + 2] = f2bf(w.z); lds[row][c4 + 3] = f2bf(w.w);
  }
}

// ---------------------------------------------------------------------------
// x f32 [B][C][N] -> xT bf16 [B][N][C]
// ---------------------------------------------------------------------------
__global__ __launch_bounds__(256) void transpose_kernel(
    const float* __restrict__ x, ushort* __restrict__ xT)
{
  __shared__ ushort ls[64][68];
  const int t = threadIdx.x;
  const int ntile = blockIdx.x * 64, ctile = blockIdx.y * 64, b = blockIdx.z;
  const float* xb = x + ((size_t)b * CCH + ctile) * NTOK + ntile;
  #pragma unroll
  for (int p = 0; p < 4; ++p) {
    int idx = p * 256 + t;
    int cc = idx >> 4, n4 = (idx & 15) * 4;
    float4 v = *(const float4*)(xb + (size_t)cc * NTOK + n4);
    ls[cc][n4 + 0] = f2bf(v.x); ls[cc][n4 + 1] = f2bf(v.y);
    ls[cc][n4 + 2] = f2bf(v.z); ls[cc][n4 + 3] = f2bf(v.w);
  }
  __syncthreads();
  ushort* ob = xT + ((size_t)b * NTOK + ntile) * CCH + ctile;
  #pragma unroll
  for (int p = 0; p < 16; ++p) {
    int idx = p * 256 + t;
    int nn = idx >> 6, cc = idx & 63;
    ob[(size_t)nn * CCH + cc] = ls[cc][nn];
  }
}

// ---------------------------------------------------------------------------
// qkv via MFMA. which=0: qT[n][o], 1: kT[n][o] (A=xT tile, B=W), 2: v[o][n]
// (A=W, B=xT tile). blockIdx.z = lidx*B + b, layer = l0+lidx.
// ---------------------------------------------------------------------------
__global__ __launch_bounds__(256) void qkv_kernel(
    const ushort* __restrict__ xT,
    const float* __restrict__ W1, const float* __restrict__ b1,
    const float* __restrict__ W2, const float* __restrict__ b2,
    const float* __restrict__ Wg, const float* __restrict__ bg,
    ushort* __restrict__ qT, ushort* __restrict__ kT, ushort* __restrict__ vb,
    int l0)
{
  __shared__ ushort as[128][LDP];
  __shared__ ushort bs[128][LDP];
  const int t = threadIdx.x;
  const int ntile = blockIdx.x * 128;
  const int which = blockIdx.y;
  const int z = blockIdx.z;
  const int b = z & 1, lidx = z >> 1, layer = l0 + lidx;
  const float* W; const float* bias; ushort* out;
  if (which == 0)      { W = W1; bias = b1; out = qT; }
  else if (which == 1) { W = W2; bias = b2; out = kT; }
  else                 { W = Wg; bias = bg; out = vb; }
  W += (size_t)layer * CCH * CCH; bias += (size_t)layer * CCH;
  const ushort* xb = xT + ((size_t)b * NTOK + ntile) * CCH;
  ushort* oz = out + (size_t)z * NTOK * CCH;

  if (which < 2) { stage_bf16(as, xb, CCH, t); stage_f32(bs, W, t); }
  else           { stage_f32(as, W, t);        stage_bf16(bs, xb, CCH, t); }
  __syncthreads();

  const int lane = t & 63, wave = t >> 6;
  const int l16 = lane & 15, lg = lane >> 4;
  const int wr = (wave >> 1) * 64, wc = (wave & 1) * 64;

  f32x4 acc[4][4];
  #pragma unroll
  for (int i = 0; i < 4; ++i)
    #pragma unroll
    for (int j = 0; j < 4; ++j) acc[i][j] = (f32x4)0.f;

  #pragma unroll
  for (int kk = 0; kk < 4; ++kk) {
    bf16x8 a[4], bb[4];
    #pragma unroll
    for (int i = 0; i < 4; ++i)
      a[i] = *(const bf16x8*)&as[wr + i * 16 + l16][kk * 32 + lg * 8];
    #pragma unroll
    for (int j = 0; j < 4; ++j)
      bb[j] = *(const bf16x8*)&bs[wc + j * 16 + l16][kk * 32 + lg * 8];
    #pragma unroll
    for (int i = 0; i < 4; ++i)
      #pragma unroll
      for (int j = 0; j < 4; ++j)
        acc[i][j] = __builtin_amdgcn_mfma_f32_16x16x32_bf16(a[i], bb[j], acc[i][j], 0, 0, 0);
  }

  if (which < 2) {   // out[n][o], bias along col o
    #pragma unroll
    for (int j = 0; j < 4; ++j) {
      float bv = bias[wc + j * 16 + l16];
      #pragma unroll
      for (int i = 0; i < 4; ++i)
        #pragma unroll
        for (int r = 0; r < 4; ++r) {
          int n = ntile + wr + i * 16 + lg * 4 + r;
          oz[(size_t)n * CCH + wc + j * 16 + l16] = f2bf(acc[i][j][r] + bv);
        }
    }
  } else {           // v[o][n], bias along row o
    #pragma unroll
    for (int i = 0; i < 4; ++i)
      #pragma unroll
      for (int r = 0; r < 4; ++r) {
        int o = wr + i * 16 + lg * 4 + r;
        float bv = bias[o];
        #pragma unroll
        for (int j = 0; j < 4; ++j)
          oz[(size_t)o * NTOK + ntile + wc + j * 16 + l16] = f2bf(acc[i][j][r] + bv);
      }
  }
}

// ---------------------------------------------------------------------------
// dcol: D[z][m] += sum_n exp(S[n][m]*scale), S = qT . kT^T (K=C), MFMA tiles.
// ---------------------------------------------------------------------------
__global__ __launch_bounds__(256) void dcol_kernel(
    const ushort* __restrict__ qT, const ushort* __restrict__ kT,
    float* __restrict__ D)
{
  __shared__ ushort qs[128][LDP];
  __shared__ ushort ks[128][LDP];
  const int t = threadIdx.x;
  const int ntile = blockIdx.x * 128, mtile = blockIdx.y * 128;
  const int z = blockIdx.z;
  stage_bf16(qs, qT + ((size_t)z * NTOK + ntile) * CCH, CCH, t);
  stage_bf16(ks, kT + ((size_t)z * NTOK + mtile) * CCH, CCH, t);
  __syncthreads();

  const int lane = t & 63, wave = t >> 6;
  const int l16 = lane & 15, lg = lane >> 4;
  const int wr = (wave >> 1) * 64, wc = (wave & 1) * 64;

  f32x4 acc[4][4];
  #pragma unroll
  for (int i = 0; i < 4; ++i)
    #pragma unroll
    for (int j = 0; j < 4; ++j) acc[i][j] = (f32x4)0.f;

  #pragma unroll
  for (int kk = 0; kk < 4; ++kk) {
    bf16x8 a[4], bb[4];
    #pragma unroll
    for (int i = 0; i < 4; ++i)
      a[i] = *(const bf16x8*)&qs[wr + i * 16 + l16][kk * 32 + lg * 8];
    #pragma unroll
    for (int j = 0; j < 4; ++j)
      bb[j] = *(const bf16x8*)&ks[wc + j * 16 + l16][kk * 32 + lg * 8];
    #pragma unroll
    for (int i = 0; i < 4; ++i)
      #pragma unroll
      for (int j = 0; j < 4; ++j)
        acc[i][j] = __builtin_amdgcn_mfma_f32_16x16x32_bf16(a[i], bb[j], acc[i][j], 0, 0, 0);
  }

  float* Dz = D + (size_t)z * NTOK;
  #pragma unroll
  for (int j = 0; j < 4; ++j) {
    float cs = 0.f;
    #pragma unroll
    for (int i = 0; i < 4; ++i)
      #pragma unroll
      for (int r = 0; r < 4; ++r)
        cs += __expf(acc[i][j][r] * INV_SQRT);
    cs += __shfl_xor(cs, 16);
    cs += __shfl_xor(cs, 32);
    if (lg == 0) atomicAdd(&Dz[mtile + wc + j * 16 + l16], cs);
  }
}

// ---------------------------------------------------------------------------
// rD = 1 / (D * L)
// ---------------------------------------------------------------------------
__global__ __launch_bounds__(256) void rdk_kernel(
    const float* __restrict__ D, float* __restrict__ rD)
{
  int i = blockIdx.x * 256 + threadIdx.x;
  rD[i] = 1.0f / (D[i] * (float)NLAY);
}

// ---------------------------------------------------------------------------
// pv: acc[b][n][c] += sum_m exp(S[n][m]*scale)*rD[m] * v[c][m]
// Q in registers; S recomputed by MFMA; E' bounced through LDS; PV by MFMA.
// Waves split the 128-row n-tile: wave w owns rows [w*32, w*32+32).
// ---------------------------------------------------------------------------
__global__ __launch_bounds__(256) void pv_kernel(
    const ushort* __restrict__ qT, const ushort* __restrict__ kT,
    const ushort* __restrict__ vb, const float* __restrict__ rD,
    float* __restrict__ accG, int msubs)
{
  __shared__ ushort kv[128][LDP];   // K-tile, then reused as V-tile
  __shared__ ushort es[128][LDP];   // E' tile [n][m]
  __shared__ float  rds[128];
  const int t = threadIdx.x;
  const int ntile  = blockIdx.x * 128;
  const int z      = blockIdx.z;
  const int b      = z & 1;
  const int mstart = blockIdx.y * msubs * 128;
  const ushort* qz = qT + (size_t)z * NTOK * CCH;
  const ushort* kz = kT + (size_t)z * NTOK * CCH;
  const ushort* vz = vb + (size_t)z * NTOK * CCH;
  const float* rdz = rD + (size_t)z * NTOK;

  const int lane = t & 63, wave = t >> 6;
  const int l16 = lane & 15, lg = lane >> 4;
  const int nw = wave * 32;

  // Q fragments held in registers for the whole block
  bf16x8 aq[2][4];
  #pragma unroll
  for (int i = 0; i < 2; ++i)
    #pragma unroll
    for (int kk = 0; kk < 4; ++kk)
      aq[i][kk] = *(const bf16x8*)(qz + (size_t)(ntile + nw + i * 16 + l16) * CCH
                                   + kk * 32 + lg * 8);

  f32x4 oacc[2][8];
  #pragma unroll
  for (int i = 0; i < 2; ++i)
    #pragma unroll
    for (int cf = 0; cf < 8; ++cf) oacc[i][cf] = (f32x4)0.f;

  for (int st = 0; st < msubs; ++st) {
    const int msub = mstart + st * 128;
    stage_bf16(kv, kz + (size_t)msub * CCH, CCH, t);
    if (t < 128) rds[t] = rdz[msub + t];
    __syncthreads();

    // S phase: sacc[i][mf] over wave's 32 n-rows x 128 m
    f32x4 sacc[2][8];
    #pragma unroll
    for (int i = 0; i < 2; ++i)
      #pragma unroll
      for (int mf = 0; mf < 8; ++mf) sacc[i][mf] = (f32x4)0.f;
    #pragma unroll
    for (int kk = 0; kk < 4; ++kk) {
      #pragma unroll
      for (int mh = 0; mh < 2; ++mh) {   // split mf loop to cap live b-frags
        bf16x8 bk[4];
        #pragma unroll
        for (int mj = 0; mj < 4; ++mj)
          bk[mj] = *(const bf16x8*)&kv[(mh * 4 + mj) * 16 + l16][kk * 32 + lg * 8];
        #pragma unroll
        for (int i = 0; i < 2; ++i)
          #pragma unroll
          for (int mj = 0; mj < 4; ++mj)
            sacc[i][mh * 4 + mj] = __builtin_amdgcn_mfma_f32_16x16x32_bf16(
                aq[i][kk], bk[mj], sacc[i][mh * 4 + mj], 0, 0, 0);
      }
    }
    // E' = exp(S*scale) * rD[m] -> es[n][m] bf16
    #pragma unroll
    for (int mf = 0; mf < 8; ++mf) {
      float rdv = rds[mf * 16 + l16];
      #pragma unroll
      for (int i = 0; i < 2; ++i)
        #pragma unroll
        for (int r = 0; r < 4; ++r)
          es[nw + i * 16 + lg * 4 + r][mf * 16 + l16] =
              f2bf(__expf(sacc[i][mf][r] * INV_SQRT) * rdv);
    }
    __syncthreads();
    stage_bf16(kv, vz + msub, NTOK, t);   // V tile: rows c, cols m (stride NTOK)
    __syncthreads();

    // PV phase: oacc[i][cf] += es-tile x V-tile
    #pragma unroll
    for (int kk = 0; kk < 4; ++kk) {
      bf16x8 ae[2];
      #pragma unroll
      for (int i = 0; i < 2; ++i)
        ae[i] = *(const bf16x8*)&es[nw + i * 16 + l16][kk * 32 + lg * 8];
      #pragma unroll
      for (int ch = 0; ch < 2; ++ch) {
        bf16x8 bv[4];
        #pragma unroll
        for (int cj = 0; cj < 4; ++cj)
          bv[cj] = *(const bf16x8*)&kv[(ch * 4 + cj) * 16 + l16][kk * 32 + lg * 8];
        #pragma unroll
        for (int i = 0; i < 2; ++i)
          #pragma unroll
          for (int cj = 0; cj < 4; ++cj)
            oacc[i][ch * 4 + cj] = __builtin_amdgcn_mfma_f32_16x16x32_bf16(
                ae[i], bv[cj], oacc[i][ch * 4 + cj], 0, 0, 0);
      }
    }
    __syncthreads();
  }

  float* az = accG + ((size_t)b * NTOK + ntile) * CCH;
  #pragma unroll
  for (int i = 0; i < 2; ++i)
    #pragma unroll
    for (int cf = 0; cf < 8; ++cf)
      #pragma unroll
      for (int r = 0; r < 4; ++r)
        atomicAdd(&az[(size_t)(nw + i * 16 + lg * 4 + r) * CCH + cf * 16 + l16],
                  oacc[i][cf][r]);
}

// ---------------------------------------------------------------------------
// out[b][c][n] = acc[b][n][c] + x[b][c][n]
// ---------------------------------------------------------------------------
__global__ __launch_bounds__(256) void finalize_kernel(
    const float* __restrict__ acc, const float* __restrict__ x,
    float* __restrict__ out)
{
  __shared__ float ts[64][65];
  const int t = threadIdx.x;
  const int ntile = blockIdx.x * 64, ctile = blockIdx.y * 64, b = blockIdx.z;
  const float* ab = acc + ((size_t)b * NTOK + ntile) * CCH + ctile;
  #pragma unroll
  for (int p = 0; p < 4; ++p) {
    int idx = p * 256 + t;
    int nn = idx >> 4, c4 = (idx & 15) * 4;
    float4 v = *(const float4*)(ab + (size_t)nn * CCH + c4);
    ts[nn][c4 + 0] = v.x; ts[nn][c4 + 1] = v.y;
    ts[nn][c4 + 2] = v.z; ts[nn][c4 + 3] = v.w;
  }
  __syncthreads();
  const size_t base = ((size_t)b * CCH + ctile) * NTOK + ntile;
  #pragma unroll
  for (int p = 0; p < 16; ++p) {
    int idx = p * 256 + t;
    int nn = idx & 63, cc = idx >> 6;
    size_t o = base + (size_t)cc * NTOK + nn;
    out[o] = ts[nn][cc] + x[o];
  }
}

// ---------------------------------------------------------------------------
extern "C" void kernel_launch(void* const* d_in, const int* in_sizes, int n_in,
                              void* d_out, int out_size, void* d_ws, size_t ws_size,
                              hipStream_t stream)
{
  const float* x  = (const float*)d_in[0];
  const float* W1 = (const float*)d_in[1];
  const float* b1 = (const float*)d_in[2];
  const float* W2 = (const float*)d_in[3];
  const float* b2 = (const float*)d_in[4];
  const float* Wg = (const float*)d_in[5];
  const float* bg = (const float*)d_in[6];
  float* out = (float*)d_out;

  const size_t PL = (size_t)BCNT * NTOK * CCH;   // 1,048,576 elements per slab
  const size_t DSZ = (size_t)BCNT * NTOK;        // 8192

  // nbuf=6: all layers get private buffers (one dispatch per stage).
  size_t need6 = PL * 2 + 3 * 6 * PL * 2 + 2 * 6 * DSZ * 4 + PL * 4;
  int nb = (ws_size >= need6) ? 6 : 1;

  char* p = (char*)d_ws;
  ushort* xT = (ushort*)p; p += PL * 2;
  ushort* qT = (ushort*)p; p += (size_t)nb * PL * 2;
  ushort* kT = (ushort*)p; p += (size_t)nb * PL * 2;
  ushort* vv = (ushort*)p; p += (size_t)nb * PL * 2;
  float*  D  = (float*)p;  p += (size_t)nb * DSZ * 4;
  float*  rDp= (float*)p;  p += (size_t)nb * DSZ * 4;
  float*  acc= (float*)p;  p += PL * 4;

  hipMemsetAsync(acc, 0, PL * 4, stream);
  transpose_kernel<<<dim3(NTOK / 64, CCH / 64, BCNT), 256, 0, stream>>>(x, xT);

  for (int l0 = 0; l0 < NLAY; l0 += nb) {
    const int LB = nb * BCNT;
    hipMemsetAsync(D, 0, (size_t)LB * NTOK * 4, stream);
    qkv_kernel<<<dim3(NTOK / 128, 3, LB), 256, 0, stream>>>(
        xT, W1, b1, W2, b2, Wg, bg, qT, kT, vv, l0);
    dcol_kernel<<<dim3(NTOK / 128, NTOK / 128, LB), 256, 0, stream>>>(qT, kT, D);
    rdk_kernel<<<dim3(LB * NTOK / 256), 256, 0, stream>>>(D, rDp);
    const int ms = (nb == 6) ? 2 : 8;
    pv_kernel<<<dim3(NTOK / 128, ms, LB), 256, 0, stream>>>(
        qT, kT, vv, rDp, acc, NTOK / (ms * 128));
  }
  finalize_kernel<<<dim3(NTOK / 64, CCH / 64, BCNT), 256, 0, stream>>>(acc, x, out);
}

// Round 3
// 302.425 us; speedup vs baseline: 11.3692x; 1.4328x over previous
//
#include <hip/hip_runtime.h>
#include <hip/hip_bf16.h>

// Problem constants (B,C,T,H,W = 2,128,4,32,32; L=6; N=T*H*W=4096)
#define BCNT 2
#define CCH  128
#define NTOK 4096
#define NLAY 6
#define INV_SQRT 0.015625f   // 1/sqrt(4096)
#define LDP 136              // padded LDS cols for 128-wide bf16 tiles

using f32x4  = __attribute__((ext_vector_type(4))) float;
using bf16x8 = __attribute__((ext_vector_type(8))) short;

static __device__ __forceinline__ ushort f2bf(float f) {
  unsigned u = __float_as_uint(f);
  u += 0x7FFF + ((u >> 16) & 1);   // RNE
  return (ushort)(u >> 16);
}
static __device__ __forceinline__ uint packbf(float lo, float hi) {
  return ((uint)f2bf(hi) << 16) | (uint)f2bf(lo);
}
// async 16B/lane global->LDS DMA (LDS dest = wave-uniform base + lane*16)
static __device__ __forceinline__ void dma16(const void* g, void* l) {
  __builtin_amdgcn_global_load_lds(
      (const __attribute__((address_space(1))) unsigned int*)g,
      (__attribute__((address_space(3))) unsigned int*)l, 16, 0, 0);
}

// Stage a 128x128 bf16 tile (global row stride = gstride ushorts) into lds[128][LDP].
static __device__ __forceinline__ void stage_bf16(ushort (*lds)[LDP],
                                                  const ushort* __restrict__ g,
                                                  int gstride, int t) {
  #pragma unroll
  for (int p = 0; p < 8; ++p) {
    int idx = p * 256 + t;
    int row = idx >> 4, ch = (idx & 15) * 8;
    *(uint4*)&lds[row][ch] = *(const uint4*)(g + (size_t)row * gstride + ch);
  }
}

// Stage a 128x128 f32 tile (row stride 128) into lds bf16 [128][LDP].
static __device__ __forceinline__ void stage_f32(ushort (*lds)[LDP],
                                                 const float* __restrict__ g, int t) {
  #pragma unroll
  for (int p = 0; p < 16; ++p) {
    int idx = p * 256 + t;
    int row = idx >> 5, c4 = (idx & 31) * 4;
    float4 w = *(const float4*)(g + row * 128 + c4);
    lds[row][c4 + 0] = f2bf(w.x); lds[row][c4 + 1] = f2bf(w.y);
    lds[row][c4 + 2] = f2bf(w.z); lds[row][c4 + 3] = f2bf(w.w);
  }
}

// ---------------------------------------------------------------------------
// x f32 [B][C][N] -> xT bf16 [B][N][C]
// ---------------------------------------------------------------------------
__global__ __launch_bounds__(256) void transpose_kernel(
    const float* __restrict__ x, ushort* __restrict__ xT)
{
  __shared__ ushort ls[64][68];
  const int t = threadIdx.x;
  const int ntile = blockIdx.x * 64, ctile = blockIdx.y * 64, b = blockIdx.z;
  const float* xb = x + ((size_t)b * CCH + ctile) * NTOK + ntile;
  #pragma unroll
  for (int p = 0; p < 4; ++p) {
    int idx = p * 256 + t;
    int cc = idx >> 4, n4 = (idx & 15) * 4;
    float4 v = *(const float4*)(xb + (size_t)cc * NTOK + n4);
    ls[cc][n4 + 0] = f2bf(v.x); ls[cc][n4 + 1] = f2bf(v.y);
    ls[cc][n4 + 2] = f2bf(v.z); ls[cc][n4 + 3] = f2bf(v.w);
  }
  __syncthreads();
  ushort* ob = xT + ((size_t)b * NTOK + ntile) * CCH + ctile;
  #pragma unroll
  for (int p = 0; p < 16; ++p) {
    int idx = p * 256 + t;
    int nn = idx >> 6, cc = idx & 63;
    ob[(size_t)nn * CCH + cc] = ls[cc][nn];
  }
}

// ---------------------------------------------------------------------------
// qkv via MFMA. which=0: qT[n][o], 1: kT[n][o] (A=xT tile, B=W), 2: v[o][n]
// (A=W, B=xT tile). blockIdx.z = lidx*B + b, layer = l0+lidx.
// ---------------------------------------------------------------------------
__global__ __launch_bounds__(256) void qkv_kernel(
    const ushort* __restrict__ xT,
    const float* __restrict__ W1, const float* __restrict__ b1,
    const float* __restrict__ W2, const float* __restrict__ b2,
    const float* __restrict__ Wg, const float* __restrict__ bg,
    ushort* __restrict__ qT, ushort* __restrict__ kT, ushort* __restrict__ vb,
    int l0)
{
  __shared__ ushort as[128][LDP];
  __shared__ ushort bs[128][LDP];
  const int t = threadIdx.x;
  const int ntile = blockIdx.x * 128;
  const int which = blockIdx.y;
  const int z = blockIdx.z;
  const int b = z & 1, lidx = z >> 1, layer = l0 + lidx;
  const float* W; const float* bias; ushort* out;
  if (which == 0)      { W = W1; bias = b1; out = qT; }
  else if (which == 1) { W = W2; bias = b2; out = kT; }
  else                 { W = Wg; bias = bg; out = vb; }
  W += (size_t)layer * CCH * CCH; bias += (size_t)layer * CCH;
  const ushort* xb = xT + ((size_t)b * NTOK + ntile) * CCH;
  ushort* oz = out + (size_t)z * NTOK * CCH;

  if (which < 2) { stage_bf16(as, xb, CCH, t); stage_f32(bs, W, t); }
  else           { stage_f32(as, W, t);        stage_bf16(bs, xb, CCH, t); }
  __syncthreads();

  const int lane = t & 63, wave = t >> 6;
  const int l16 = lane & 15, lg = lane >> 4;
  const int wr = (wave >> 1) * 64, wc = (wave & 1) * 64;

  f32x4 acc[4][4];
  #pragma unroll
  for (int i = 0; i < 4; ++i)
    #pragma unroll
    for (int j = 0; j < 4; ++j) acc[i][j] = (f32x4)0.f;

  #pragma unroll
  for (int kk = 0; kk < 4; ++kk) {
    bf16x8 a[4], bb[4];
    #pragma unroll
    for (int i = 0; i < 4; ++i)
      a[i] = *(const bf16x8*)&as[wr + i * 16 + l16][kk * 32 + lg * 8];
    #pragma unroll
    for (int j = 0; j < 4; ++j)
      bb[j] = *(const bf16x8*)&bs[wc + j * 16 + l16][kk * 32 + lg * 8];
    #pragma unroll
    for (int i = 0; i < 4; ++i)
      #pragma unroll
      for (int j = 0; j < 4; ++j)
        acc[i][j] = __builtin_amdgcn_mfma_f32_16x16x32_bf16(a[i], bb[j], acc[i][j], 0, 0, 0);
  }

  if (which < 2) {   // out[n][o], bias along col o
    #pragma unroll
    for (int j = 0; j < 4; ++j) {
      float bv = bias[wc + j * 16 + l16];
      #pragma unroll
      for (int i = 0; i < 4; ++i)
        #pragma unroll
        for (int r = 0; r < 4; ++r) {
          int n = ntile + wr + i * 16 + lg * 4 + r;
          oz[(size_t)n * CCH + wc + j * 16 + l16] = f2bf(acc[i][j][r] + bv);
        }
    }
  } else {           // v[o][n], bias along row o
    #pragma unroll
    for (int i = 0; i < 4; ++i)
      #pragma unroll
      for (int r = 0; r < 4; ++r) {
        int o = wr + i * 16 + lg * 4 + r;
        float bv = bias[o];
        #pragma unroll
        for (int j = 0; j < 4; ++j)
          oz[(size_t)o * NTOK + ntile + wc + j * 16 + l16] = f2bf(acc[i][j][r] + bv);
      }
  }
}

// ---------------------------------------------------------------------------
// dcol: D[z][m] += sum_n exp(S[n][m]*scale), S = qT . kT^T (K=C), MFMA tiles.
// ---------------------------------------------------------------------------
__global__ __launch_bounds__(256) void dcol_kernel(
    const ushort* __restrict__ qT, const ushort* __restrict__ kT,
    float* __restrict__ D)
{
  __shared__ ushort qs[128][LDP];
  __shared__ ushort ks[128][LDP];
  const int t = threadIdx.x;
  const int ntile = blockIdx.x * 128, mtile = blockIdx.y * 128;
  const int z = blockIdx.z;
  stage_bf16(qs, qT + ((size_t)z * NTOK + ntile) * CCH, CCH, t);
  stage_bf16(ks, kT + ((size_t)z * NTOK + mtile) * CCH, CCH, t);
  __syncthreads();

  const int lane = t & 63, wave = t >> 6;
  const int l16 = lane & 15, lg = lane >> 4;
  const int wr = (wave >> 1) * 64, wc = (wave & 1) * 64;

  f32x4 acc[4][4];
  #pragma unroll
  for (int i = 0; i < 4; ++i)
    #pragma unroll
    for (int j = 0; j < 4; ++j) acc[i][j] = (f32x4)0.f;

  #pragma unroll
  for (int kk = 0; kk < 4; ++kk) {
    bf16x8 a[4], bb[4];
    #pragma unroll
    for (int i = 0; i < 4; ++i)
      a[i] = *(const bf16x8*)&qs[wr + i * 16 + l16][kk * 32 + lg * 8];
    #pragma unroll
    for (int j = 0; j < 4; ++j)
      bb[j] = *(const bf16x8*)&ks[wc + j * 16 + l16][kk * 32 + lg * 8];
    #pragma unroll
    for (int i = 0; i < 4; ++i)
      #pragma unroll
      for (int j = 0; j < 4; ++j)
        acc[i][j] = __builtin_amdgcn_mfma_f32_16x16x32_bf16(a[i], bb[j], acc[i][j], 0, 0, 0);
  }

  float* Dz = D + (size_t)z * NTOK;
  #pragma unroll
  for (int j = 0; j < 4; ++j) {
    float cs = 0.f;
    #pragma unroll
    for (int i = 0; i < 4; ++i)
      #pragma unroll
      for (int r = 0; r < 4; ++r)
        cs += __expf(acc[i][j][r] * INV_SQRT);
    cs += __shfl_xor(cs, 16);
    cs += __shfl_xor(cs, 32);
    if (lg == 0) atomicAdd(&Dz[mtile + wc + j * 16 + l16], cs);
  }
}

// ---------------------------------------------------------------------------
// rD = 1 / (D * L)
// ---------------------------------------------------------------------------
__global__ __launch_bounds__(256) void rdk_kernel(
    const float* __restrict__ D, float* __restrict__ rD)
{
  int i = blockIdx.x * 256 + threadIdx.x;
  rD[i] = 1.0f / (D[i] * (float)NLAY);
}

// ---------------------------------------------------------------------------
// scalev: v[z][c][m] *= rD[z][m]  (bf16 in-place, 8 elems/thread)
// ---------------------------------------------------------------------------
__global__ __launch_bounds__(256) void scalev_kernel(
    ushort* __restrict__ vv, const float* __restrict__ rD)
{
  size_t i8 = ((size_t)blockIdx.x * 256 + threadIdx.x) * 8;
  int m = (int)(i8 & (NTOK - 1));
  int z = (int)(i8 >> 19);               // per-z elems = C*N = 2^19
  const float* rd = rD + (size_t)z * NTOK + m;
  uint4 u = *(uint4*)(vv + i8);
  float4 r0 = *(const float4*)rd;
  float4 r1 = *(const float4*)(rd + 4);
  uint w[4] = {u.x, u.y, u.z, u.w};
  float rs[8] = {r0.x, r0.y, r0.z, r0.w, r1.x, r1.y, r1.z, r1.w};
  #pragma unroll
  for (int d = 0; d < 4; ++d) {
    float lo = __uint_as_float(w[d] << 16) * rs[2 * d];
    float hi = __uint_as_float(w[d] & 0xFFFF0000u) * rs[2 * d + 1];
    w[d] = ((uint)f2bf(hi) << 16) | (uint)f2bf(lo);
  }
  *(uint4*)(vv + i8) = make_uint4(w[0], w[1], w[2], w[3]);
}

// ---------------------------------------------------------------------------
// pv: acc[b][n][c] += sum_m exp(S[n][m]*scale) * v'[c][m]   (v' = v/(D*L))
// Swapped S^T (mfma(K,Q)) -> P-row lane-local -> in-register E A-frag build
// (pack + 8 shfl + 4 sel per 32-m block). K/V DMA-staged double-buffered via
// global_load_lds with pre-swizzled source; 2-phase counted schedule.
// K tile: ks[p][m=64][c=128] (16B-block col ^ (row&15)); V: vs[p][c=128][m=64]
// (8B-slot ^ (c&7)). LDS 64KB -> 2 blocks/CU. grid (32 ntiles, 4, z).
// ---------------------------------------------------------------------------
__global__ __launch_bounds__(256, 2) void pv_kernel(
    const ushort* __restrict__ qT, const ushort* __restrict__ kT,
    const ushort* __restrict__ vv, float* __restrict__ accG)
{
  __shared__ ushort ks[2][64][128];
  __shared__ ushort vs[2][128][64];
  const int t = threadIdx.x;
  const int lane = t & 63, wave = t >> 6;
  const int l16 = lane & 15, lg = lane >> 4;
  const int ntile = blockIdx.x * 128;
  const int z = blockIdx.z, b = z & 1;
  const int mstart = blockIdx.y * 1024;   // 16 subtiles of 64 m
  const ushort* qz = qT + (size_t)z * NTOK * CCH;
  const ushort* kz = kT + (size_t)z * NTOK * CCH;
  const ushort* vz = vv + (size_t)z * NTOK * CCH;
  const int nw = wave * 32;

  // Q fragments (B-operand): lane holds Q[n=ntile+nw+i*16+l16][c=kk*32+lg*8+j]
  bf16x8 qf[2][4];
  #pragma unroll
  for (int i = 0; i < 2; ++i)
    #pragma unroll
    for (int kk = 0; kk < 4; ++kk)
      qf[i][kk] = *(const bf16x8*)(qz + (size_t)(ntile + nw + i * 16 + l16) * CCH
                                   + kk * 32 + lg * 8);

  f32x4 oacc[2][8];
  #pragma unroll
  for (int i = 0; i < 2; ++i)
    #pragma unroll
    for (int cf = 0; cf < 8; ++cf) oacc[i][cf] = (f32x4)0.f;

#define STAGE(p, msub) do {                                                   \
    _Pragma("unroll")                                                         \
    for (int j_ = 0; j_ < 4; ++j_) {                                          \
      int row_ = wave * 16 + j_ * 4 + (lane >> 4);                            \
      dma16(kz + (size_t)((msub) + row_) * CCH + (((lane & 15) ^ (row_ & 15)) * 8), \
            &ks[p][wave * 16 + j_ * 4][0]);                                   \
      int c_ = wave * 32 + j_ * 8 + (lane >> 3);                              \
      dma16(vz + (size_t)c_ * NTOK + (msub) + (((lane & 7) ^ (c_ & 7)) * 8),  \
            &vs[p][wave * 32 + j_ * 8][0]);                                   \
    }                                                                         \
  } while (0)

  int cur = 0;
  STAGE(0, mstart);
  asm volatile("s_waitcnt vmcnt(0)" ::: "memory");
  __builtin_amdgcn_s_barrier();

  for (int st = 0; st < 16; ++st) {
    if (st < 15) STAGE(cur ^ 1, mstart + (st + 1) * 64);

    // ---- S^T phase: sacc[mf][i]; lane holds S[n=nw+i*16+l16][m=mf*16+lg*4+r]
    f32x4 sacc[4][2];
    #pragma unroll
    for (int mf = 0; mf < 4; ++mf)
      #pragma unroll
      for (int i = 0; i < 2; ++i) sacc[mf][i] = (f32x4)0.f;
    #pragma unroll
    for (int kk = 0; kk < 4; ++kk) {
      bf16x8 kf[4];
      #pragma unroll
      for (int mf = 0; mf < 4; ++mf)
        kf[mf] = *(const bf16x8*)&ks[cur][mf * 16 + l16][((kk * 4 + lg) ^ l16) * 8];
      #pragma unroll
      for (int mf = 0; mf < 4; ++mf)
        #pragma unroll
        for (int i = 0; i < 2; ++i)
          sacc[mf][i] = __builtin_amdgcn_mfma_f32_16x16x32_bf16(
              kf[mf], qf[i][kk], sacc[mf][i], 0, 0, 0);
    }
    // ---- exp
    float e[4][2][4];
    #pragma unroll
    for (int mf = 0; mf < 4; ++mf)
      #pragma unroll
      for (int i = 0; i < 2; ++i)
        #pragma unroll
        for (int r = 0; r < 4; ++r)
          e[mf][i][r] = __expf(sacc[mf][i][r] * INV_SQRT);

    // ---- build E A-frags in-register + PV MFMA, per 32-m block
    #pragma unroll
    for (int kk2 = 0; kk2 < 2; ++kk2) {
      bf16x8 vf[8];
      #pragma unroll
      for (int ch = 0; ch < 8; ++ch)
        vf[ch] = *(const bf16x8*)&vs[cur][ch * 16 + l16]
                                    [(((kk2 * 4 + lg) ^ (l16 & 7)) * 8)];
      #pragma unroll
      for (int i = 0; i < 2; ++i) {
        uint wA0 = packbf(e[2 * kk2][i][0], e[2 * kk2][i][1]);
        uint wA1 = packbf(e[2 * kk2][i][2], e[2 * kk2][i][3]);
        uint wB0 = packbf(e[2 * kk2 + 1][i][0], e[2 * kk2 + 1][i][1]);
        uint wB1 = packbf(e[2 * kk2 + 1][i][2], e[2 * kk2 + 1][i][3]);
        int s  = l16 + ((lg & 1) << 5);   // source lane (2*lg)&3 group
        int s2 = s + 16;                  // source lane (2*lg+1)&3 group
        uint a0 = (uint)__shfl((int)wA0, s),  b0 = (uint)__shfl((int)wB0, s);
        uint a1 = (uint)__shfl((int)wA1, s),  b1_ = (uint)__shfl((int)wB1, s);
        uint a2 = (uint)__shfl((int)wA0, s2), b2_ = (uint)__shfl((int)wB0, s2);
        uint a3 = (uint)__shfl((int)wA1, s2), b3 = (uint)__shfl((int)wB1, s2);
        bool loT = (lg < 2);
        int4 ei = make_int4((int)(loT ? a0 : b0), (int)(loT ? a1 : b1_),
                            (int)(loT ? a2 : b2_), (int)(loT ? a3 : b3));
        bf16x8 ef = *(bf16x8*)&ei;
        #pragma unroll
        for (int ch = 0; ch < 8; ++ch)
          oacc[i][ch] = __builtin_amdgcn_mfma_f32_16x16x32_bf16(
              ef, vf[ch], oacc[i][ch], 0, 0, 0);
      }
    }
    asm volatile("s_waitcnt vmcnt(0)" ::: "memory");
    __builtin_amdgcn_s_barrier();
    cur ^= 1;
  }
#undef STAGE

  float* az = accG + ((size_t)b * NTOK + ntile) * CCH;
  #pragma unroll
  for (int i = 0; i < 2; ++i)
    #pragma unroll
    for (int cf = 0; cf < 8; ++cf)
      #pragma unroll
      for (int r = 0; r < 4; ++r)
        atomicAdd(&az[(size_t)(nw + i * 16 + lg * 4 + r) * CCH + cf * 16 + l16],
                  oacc[i][cf][r]);
}

// ---------------------------------------------------------------------------
// out[b][c][n] = acc[b][n][c] + x[b][c][n]
// ---------------------------------------------------------------------------
__global__ __launch_bounds__(256) void finalize_kernel(
    const float* __restrict__ acc, const float* __restrict__ x,
    float* __restrict__ out)
{
  __shared__ float ts[64][65];
  const int t = threadIdx.x;
  const int ntile = blockIdx.x * 64, ctile = blockIdx.y * 64, b = blockIdx.z;
  const float* ab = acc + ((size_t)b * NTOK + ntile) * CCH + ctile;
  #pragma unroll
  for (int p = 0; p < 4; ++p) {
    int idx = p * 256 + t;
    int nn = idx >> 4, c4 = (idx & 15) * 4;
    float4 v = *(const float4*)(ab + (size_t)nn * CCH + c4);
    ts[nn][c4 + 0] = v.x; ts[nn][c4 + 1] = v.y;
    ts[nn][c4 + 2] = v.z; ts[nn][c4 + 3] = v.w;
  }
  __syncthreads();
  const size_t base = ((size_t)b * CCH + ctile) * NTOK + ntile;
  #pragma unroll
  for (int p = 0; p < 16; ++p) {
    int idx = p * 256 + t;
    int nn = idx & 63, cc = idx >> 6;
    size_t o = base + (size_t)cc * NTOK + nn;
    out[o] = ts[nn][cc] + x[o];
  }
}

// ---------------------------------------------------------------------------
extern "C" void kernel_launch(void* const* d_in, const int* in_sizes, int n_in,
                              void* d_out, int out_size, void* d_ws, size_t ws_size,
                              hipStream_t stream)
{
  const float* x  = (const float*)d_in[0];
  const float* W1 = (const float*)d_in[1];
  const float* b1 = (const float*)d_in[2];
  const float* W2 = (const float*)d_in[3];
  const float* b2 = (const float*)d_in[4];
  const float* Wg = (const float*)d_in[5];
  const float* bg = (const float*)d_in[6];
  float* out = (float*)d_out;

  const size_t PL = (size_t)BCNT * NTOK * CCH;   // 1,048,576 elements per slab
  const size_t DSZ = (size_t)BCNT * NTOK;        // 8192

  size_t need6 = PL * 2 + 3 * 6 * PL * 2 + 2 * 6 * DSZ * 4 + PL * 4;
  int nb = (ws_size >= need6) ? 6 : 1;

  char* p = (char*)d_ws;
  ushort* xT = (ushort*)p; p += PL * 2;
  ushort* qT = (ushort*)p; p += (size_t)nb * PL * 2;
  ushort* kT = (ushort*)p; p += (size_t)nb * PL * 2;
  ushort* vv = (ushort*)p; p += (size_t)nb * PL * 2;
  float*  D  = (float*)p;  p += (size_t)nb * DSZ * 4;
  float*  rDp= (float*)p;  p += (size_t)nb * DSZ * 4;
  float*  acc= (float*)p;  p += PL * 4;

  hipMemsetAsync(acc, 0, PL * 4, stream);
  transpose_kernel<<<dim3(NTOK / 64, CCH / 64, BCNT), 256, 0, stream>>>(x, xT);

  for (int l0 = 0; l0 < NLAY; l0 += nb) {
    const int LB = nb * BCNT;
    hipMemsetAsync(D, 0, (size_t)LB * NTOK * 4, stream);
    qkv_kernel<<<dim3(NTOK / 128, 3, LB), 256, 0, stream>>>(
        xT, W1, b1, W2, b2, Wg, bg, qT, kT, vv, l0);
    dcol_kernel<<<dim3(NTOK / 128, NTOK / 128, LB), 256, 0, stream>>>(qT, kT, D);
    rdk_kernel<<<dim3(LB * NTOK / 256), 256, 0, stream>>>(D, rDp);
    scalev_kernel<<<dim3(LB * 256), 256, 0, stream>>>(vv, rDp);
    pv_kernel<<<dim3(NTOK / 128, 4, LB), 256, 0, stream>>>(qT, kT, vv, acc);
  }
  finalize_kernel<<<dim3(NTOK / 64, CCH / 64, BCNT), 256, 0, stream>>>(acc, x, out);
}